// Round 2
// baseline (221.980 us; speedup 1.0000x reference)
//
#include <hip/hip_runtime.h>
#include <hip/hip_bf16.h>
#include <cstdint>

typedef unsigned short u16;
typedef __attribute__((ext_vector_type(8))) short short8;
typedef __attribute__((ext_vector_type(4))) float f32x4;

#define B_ 32
#define H_ 8
#define S_ 512
#define C_ 64

struct alignas(8) us4 { u16 x, y, z, w; };

__device__ __forceinline__ u16 f2bf(float f) {
    uint32_t u = __builtin_bit_cast(uint32_t, f);
    u += 0x7fffu + ((u >> 16) & 1u);   // RNE
    return (u16)(u >> 16);
}
__device__ __forceinline__ float bf2f(u16 h) {
    uint32_t u = ((uint32_t)h) << 16;
    return __builtin_bit_cast(float, u);
}

// ---------------- kernel 1: 4x4 inverse (adjugate) ----------------
__global__ void k_inv4(const float* __restrict__ lf, float* __restrict__ out) {
    int i = blockIdx.x * blockDim.x + threadIdx.x;   // 16384 = B*S
    const float* m = lf + (size_t)i * 16;
    float a[16];
#pragma unroll
    for (int j = 0; j < 16; ++j) a[j] = m[j];
    float inv[16];
    inv[0]  =  a[5]*a[10]*a[15] - a[5]*a[11]*a[14] - a[9]*a[6]*a[15] + a[9]*a[7]*a[14] + a[13]*a[6]*a[11] - a[13]*a[7]*a[10];
    inv[4]  = -a[4]*a[10]*a[15] + a[4]*a[11]*a[14] + a[8]*a[6]*a[15] - a[8]*a[7]*a[14] - a[12]*a[6]*a[11] + a[12]*a[7]*a[10];
    inv[8]  =  a[4]*a[9]*a[15] - a[4]*a[11]*a[13] - a[8]*a[5]*a[15] + a[8]*a[7]*a[13] + a[12]*a[5]*a[11] - a[12]*a[7]*a[9];
    inv[12] = -a[4]*a[9]*a[14] + a[4]*a[10]*a[13] + a[8]*a[5]*a[14] - a[8]*a[6]*a[13] - a[12]*a[5]*a[10] + a[12]*a[6]*a[9];
    inv[1]  = -a[1]*a[10]*a[15] + a[1]*a[11]*a[14] + a[9]*a[2]*a[15] - a[9]*a[3]*a[14] - a[13]*a[2]*a[11] + a[13]*a[3]*a[10];
    inv[5]  =  a[0]*a[10]*a[15] - a[0]*a[11]*a[14] - a[8]*a[2]*a[15] + a[8]*a[3]*a[14] + a[12]*a[2]*a[11] - a[12]*a[3]*a[10];
    inv[9]  = -a[0]*a[9]*a[15] + a[0]*a[11]*a[13] + a[8]*a[1]*a[15] - a[8]*a[3]*a[13] - a[12]*a[1]*a[11] + a[12]*a[3]*a[9];
    inv[13] =  a[0]*a[9]*a[14] - a[0]*a[10]*a[13] - a[8]*a[1]*a[14] + a[8]*a[2]*a[13] + a[12]*a[1]*a[10] - a[12]*a[2]*a[9];
    inv[2]  =  a[1]*a[6]*a[15] - a[1]*a[7]*a[14] - a[5]*a[2]*a[15] + a[5]*a[3]*a[14] + a[13]*a[2]*a[7] - a[13]*a[3]*a[6];
    inv[6]  = -a[0]*a[6]*a[15] + a[0]*a[7]*a[14] + a[4]*a[2]*a[15] - a[4]*a[3]*a[14] - a[12]*a[2]*a[7] + a[12]*a[3]*a[6];
    inv[10] =  a[0]*a[5]*a[15] - a[0]*a[7]*a[13] - a[4]*a[1]*a[15] + a[4]*a[3]*a[13] + a[12]*a[1]*a[7] - a[12]*a[3]*a[5];
    inv[14] = -a[0]*a[5]*a[14] + a[0]*a[6]*a[13] + a[4]*a[1]*a[14] - a[4]*a[2]*a[13] - a[12]*a[1]*a[6] + a[12]*a[2]*a[5];
    inv[3]  = -a[1]*a[6]*a[11] + a[1]*a[7]*a[10] + a[5]*a[2]*a[11] - a[5]*a[3]*a[10] - a[9]*a[2]*a[7] + a[9]*a[3]*a[6];
    inv[7]  =  a[0]*a[6]*a[11] - a[0]*a[7]*a[10] - a[4]*a[2]*a[11] + a[4]*a[3]*a[10] + a[8]*a[2]*a[7] - a[8]*a[3]*a[6];
    inv[11] = -a[0]*a[5]*a[11] + a[0]*a[7]*a[9] + a[4]*a[1]*a[11] - a[4]*a[3]*a[9] - a[8]*a[1]*a[7] + a[8]*a[3]*a[5];
    inv[15] =  a[0]*a[5]*a[10] - a[0]*a[6]*a[9] - a[4]*a[1]*a[10] + a[4]*a[2]*a[9] + a[8]*a[1]*a[6] - a[8]*a[2]*a[5];
    float det = a[0]*inv[0] + a[1]*inv[4] + a[2]*inv[8] + a[3]*inv[12];
    float rd = 1.0f / det;
    float* o = out + (size_t)i * 16;
#pragma unroll
    for (int j = 0; j < 16; ++j) o[j] = inv[j] * rd;
}

// ---------------- kernel 2: transform q/k rows -> bf16 row-major ----------------
// y_i = sum_j M[i][j] x_j ; use_eta applies eta*M*eta sign pattern; scale baked in.
__global__ void k_transform(const float* __restrict__ src, u16* __restrict__ dst,
                            const float* __restrict__ invm, float scale, int use_eta) {
    int id = blockIdx.x * blockDim.x + threadIdx.x;   // [0, B*H*S*16)
    int slot = id & 15;
    int row  = id >> 4;                // [0, B*H*S)
    int n = row & (S_ - 1);
    int b = row >> 12;                 // row / (H*S)
    const float* M = invm + ((size_t)(b * S_ + n)) * 16;
    f32x4 x = *((const f32x4*)src + (size_t)row * 16 + slot);
    float y0, y1, y2, y3;
    if (slot < 4) {
        y0 = x[0]; y1 = x[1]; y2 = x[2]; y3 = x[3];
    } else {
        float x0 = x[0], x1 = x[1], x2 = x[2], x3 = x[3];
        if (use_eta) { x1 = -x1; x2 = -x2; x3 = -x3; }
        y0 = M[0]*x0 + M[1]*x1 + M[2]*x2  + M[3]*x3;
        y1 = M[4]*x0 + M[5]*x1 + M[6]*x2  + M[7]*x3;
        y2 = M[8]*x0 + M[9]*x1 + M[10]*x2 + M[11]*x3;
        y3 = M[12]*x0 + M[13]*x1 + M[14]*x2 + M[15]*x3;
        if (use_eta) { y1 = -y1; y2 = -y2; y3 = -y3; }
    }
    us4 o;
    o.x = f2bf(y0 * scale); o.y = f2bf(y1 * scale);
    o.z = f2bf(y2 * scale); o.w = f2bf(y3 * scale);
    *(us4*)(dst + (size_t)id * 4) = o;
}

// ---------------- kernel 2v: transform v and store transposed [bh][c][n] ----------------
__global__ void k_transform_v(const float* __restrict__ src, u16* __restrict__ dstT,
                              const float* __restrict__ invm) {
    __shared__ u16 tile[64 * 68];       // [n_local][c], stride 68 (8B-aligned rows)
    int bh = blockIdx.x >> 3;
    int nc = blockIdx.x & 7;
    int b = bh >> 3;
    int t = threadIdx.x;
    int slot = t & 15;
#pragma unroll
    for (int it = 0; it < 4; ++it) {
        int rl = (t >> 4) + (it << 4);          // 0..63
        int n = (nc << 6) + rl;
        int row = bh * S_ + n;
        const float* M = invm + ((size_t)(b * S_ + n)) * 16;
        f32x4 x = *((const f32x4*)src + (size_t)row * 16 + slot);
        float y0, y1, y2, y3;
        if (slot < 4) {
            y0 = x[0]; y1 = x[1]; y2 = x[2]; y3 = x[3];
        } else {
            y0 = M[0]*x[0] + M[1]*x[1] + M[2]*x[2]  + M[3]*x[3];
            y1 = M[4]*x[0] + M[5]*x[1] + M[6]*x[2]  + M[7]*x[3];
            y2 = M[8]*x[0] + M[9]*x[1] + M[10]*x[2] + M[11]*x[3];
            y3 = M[12]*x[0] + M[13]*x[1] + M[14]*x[2] + M[15]*x[3];
        }
        us4 o; o.x = f2bf(y0); o.y = f2bf(y1); o.z = f2bf(y2); o.w = f2bf(y3);
        *(us4*)&tile[rl * 68 + slot * 4] = o;
    }
    __syncthreads();
    int n0 = nc << 6;
#pragma unroll
    for (int it = 0; it < 16; ++it) {
        int i = t + (it << 8);
        int c = i >> 6;            // 0..63
        int nl = i & 63;
        dstT[((size_t)bh * 64 + c) * S_ + n0 + nl] = tile[nl * 68 + c];
    }
}

// ---------------- kernel 3: flash attention + output frame transform ----------------
__global__ __launch_bounds__(256) void k_attn(
    const u16* __restrict__ qg, const u16* __restrict__ kg,
    const u16* __restrict__ vtg, const float* __restrict__ lf,
    float* __restrict__ outp)
{
    __shared__ u16 klds[64 * 72];       // [key][c]   stride 72 (144B, 16B-aligned)
    __shared__ u16 vtlds[64 * 72];      // [c][key]   stride 72
    __shared__ float scratch[4 * 1088]; // per-wave union: P (16x72 bf16) / O (16x68 f32)

    const int bh = blockIdx.x & 255;    // swizzle: all 8 q-chunks of a bh share an XCD's L2
    const int qc = blockIdx.x >> 8;
    const int b  = bh >> 3;
    const int tid = threadIdx.x;
    const int wave = tid >> 6;
    const int lane = tid & 63;
    const int l16 = lane & 15;
    const int g4  = lane >> 4;

    u16*   pw = (u16*)(scratch + wave * 1088);
    float* ow = scratch + wave * 1088;

    const int q0 = qc * 64 + wave * 16;
    const u16* qb = qg + ((size_t)(bh * S_ + q0 + l16)) * C_ + g4 * 8;
    short8 aq0 = *(const short8*)qb;
    short8 aq1 = *(const short8*)(qb + 32);

    float mrow[4], lrow[4];
    f32x4 O[4];
#pragma unroll
    for (int r = 0; r < 4; ++r) { mrow[r] = -3.0e38f; lrow[r] = 0.f; }
#pragma unroll
    for (int nb = 0; nb < 4; ++nb) O[nb] = (f32x4){0.f, 0.f, 0.f, 0.f};

    const u16* kbase = kg  + (size_t)bh * S_ * C_;
    const u16* vbase = vtg + (size_t)bh * C_ * S_;
    const float L2E = 1.4426950408889634f;

    for (int kc = 0; kc < 8; ++kc) {
        __syncthreads();
#pragma unroll
        for (int i = tid; i < 512; i += 256) {   // K chunk: 64 keys x 64 ch
            int r = i >> 3, c8 = i & 7;
            *(short8*)&klds[r * 72 + c8 * 8] =
                *(const short8*)(kbase + ((size_t)(kc * 64 + r)) * C_ + c8 * 8);
        }
#pragma unroll
        for (int i = tid; i < 512; i += 256) {   // V^T chunk: 64 ch x 64 keys
            int c = i >> 3, k8 = i & 7;
            *(short8*)&vtlds[c * 72 + k8 * 8] =
                *(const short8*)(vbase + (size_t)c * S_ + kc * 64 + k8 * 8);
        }
        __syncthreads();

        // S = Q K^T  (scale already baked into q_g)
        f32x4 s[4];
#pragma unroll
        for (int nb = 0; nb < 4; ++nb) {
            const u16* kr = &klds[(nb * 16 + l16) * 72 + g4 * 8];
            short8 b0 = *(const short8*)kr;
            short8 b1 = *(const short8*)(kr + 32);
            f32x4 acc = (f32x4){0.f, 0.f, 0.f, 0.f};
            acc = __builtin_amdgcn_mfma_f32_16x16x32_bf16(aq0, b0, acc, 0, 0, 0);
            acc = __builtin_amdgcn_mfma_f32_16x16x32_bf16(aq1, b1, acc, 0, 0, 0);
            s[nb] = acc;
        }
        // online softmax: rows live at (g4*4 + r), cols at l16 within 16-lane group
        float alpha[4];
#pragma unroll
        for (int r = 0; r < 4; ++r) {
            float v = fmaxf(fmaxf(s[0][r], s[1][r]), fmaxf(s[2][r], s[3][r]));
            v = fmaxf(v, __shfl_xor(v, 1));
            v = fmaxf(v, __shfl_xor(v, 2));
            v = fmaxf(v, __shfl_xor(v, 4));
            v = fmaxf(v, __shfl_xor(v, 8));
            float nm = fmaxf(mrow[r], v);
            alpha[r] = exp2f((mrow[r] - nm) * L2E);
            mrow[r] = nm;
        }
        float rs[4] = {0.f, 0.f, 0.f, 0.f};
#pragma unroll
        for (int nb = 0; nb < 4; ++nb) {
#pragma unroll
            for (int r = 0; r < 4; ++r) {
                float p = exp2f((s[nb][r] - mrow[r]) * L2E);
                u16 pb = f2bf(p);
                rs[r] += bf2f(pb);   // denominator from the SAME rounded P the MFMA consumes
                pw[(g4 * 4 + r) * 72 + nb * 16 + l16] = pb;
            }
        }
#pragma unroll
        for (int r = 0; r < 4; ++r) {
            float v = rs[r];
            v += __shfl_xor(v, 1);
            v += __shfl_xor(v, 2);
            v += __shfl_xor(v, 4);
            v += __shfl_xor(v, 8);
            lrow[r] = lrow[r] * alpha[r] + v;
#pragma unroll
            for (int nb = 0; nb < 4; ++nb) O[nb][r] *= alpha[r];
        }
        // O += P V  (P A-frags from wave-private LDS; V^T rows as B-frags)
        short8 ap0 = *(const short8*)&pw[l16 * 72 + g4 * 8];
        short8 ap1 = *(const short8*)&pw[l16 * 72 + 32 + g4 * 8];
#pragma unroll
        for (int nb = 0; nb < 4; ++nb) {
            const u16* vr = &vtlds[(nb * 16 + l16) * 72 + g4 * 8];
            short8 b0 = *(const short8*)vr;
            short8 b1 = *(const short8*)(vr + 32);
            O[nb] = __builtin_amdgcn_mfma_f32_16x16x32_bf16(ap0, b0, O[nb], 0, 0, 0);
            O[nb] = __builtin_amdgcn_mfma_f32_16x16x32_bf16(ap1, b1, O[nb], 0, 0, 0);
        }
    }

    // epilogue: normalize, round-trip O through LDS, apply lframes, store f32
#pragma unroll
    for (int r = 0; r < 4; ++r) {
        float il = 1.0f / lrow[r];
#pragma unroll
        for (int nb = 0; nb < 4; ++nb)
            ow[(g4 * 4 + r) * 68 + nb * 16 + l16] = O[nb][r] * il;
    }
    // wave-private scratch: in-wave LDS ordering suffices, no barrier needed
#pragma unroll
    for (int it = 0; it < 4; ++it) {
        int rl = g4 + it * 4;
        int n = q0 + rl;
        f32x4 ov = *(const f32x4*)&ow[rl * 68 + l16 * 4];
        float y0, y1, y2, y3;
        if (l16 < 4) {
            y0 = ov[0]; y1 = ov[1]; y2 = ov[2]; y3 = ov[3];
        } else {
            const float* L = lf + ((size_t)(b * S_ + n)) * 16;
            y0 = L[0]*ov[0] + L[1]*ov[1] + L[2]*ov[2]  + L[3]*ov[3];
            y1 = L[4]*ov[0] + L[5]*ov[1] + L[6]*ov[2]  + L[7]*ov[3];
            y2 = L[8]*ov[0] + L[9]*ov[1] + L[10]*ov[2] + L[11]*ov[3];
            y3 = L[12]*ov[0] + L[13]*ov[1] + L[14]*ov[2] + L[15]*ov[3];
        }
        f32x4 o4 = (f32x4){y0, y1, y2, y3};
        *(f32x4*)(outp + ((size_t)(bh * S_ + n)) * C_ + l16 * 4) = o4;
    }
}

extern "C" void kernel_launch(void* const* d_in, const int* in_sizes, int n_in,
                              void* d_out, int out_size, void* d_ws, size_t ws_size,
                              hipStream_t stream) {
    const float* q  = (const float*)d_in[0];
    const float* k  = (const float*)d_in[1];
    const float* v  = (const float*)d_in[2];
    const float* lf = (const float*)d_in[3];
    float* out = (float*)d_out;   // reference output dtype is float32

    char* w = (char*)d_ws;
    float* invm = (float*)w;                              // 16384*16*4 = 1 MiB
    u16* qg  = (u16*)(w + (1u << 20));                    // 16 MiB
    u16* kg  = (u16*)(w + (1u << 20) + (16u << 20));      // 16 MiB
    u16* vtg = (u16*)(w + (1u << 20) + (32u << 20));      // 16 MiB (transposed [bh][c][n])

    k_inv4<<<64, 256, 0, stream>>>(lf, invm);
    k_transform<<<8192, 256, 0, stream>>>(q, qg, invm, 0.125f, 0);   // scale = 1/sqrt(64)
    k_transform<<<8192, 256, 0, stream>>>(k, kg, invm, 1.0f, 1);     // eta * inv * eta
    k_transform_v<<<2048, 256, 0, stream>>>(v, vtg, invm);
    k_attn<<<2048, 256, 0, stream>>>(qg, kg, vtg, lf, out);
}

// Round 3
// 202.943 us; speedup vs baseline: 1.0938x; 1.0938x over previous
//
#include <hip/hip_runtime.h>
#include <hip/hip_bf16.h>
#include <cstdint>

typedef unsigned short u16;
typedef __attribute__((ext_vector_type(8))) short short8;
typedef __attribute__((ext_vector_type(4))) float f32x4;

#define B_ 32
#define H_ 8
#define S_ 512
#define C_ 64

struct alignas(8) us4 { u16 x, y, z, w; };
struct alignas(8) u32x2 { uint32_t x, y; };

__device__ __forceinline__ u16 f2bf(float f) {
    uint32_t u = __builtin_bit_cast(uint32_t, f);
    u += 0x7fffu + ((u >> 16) & 1u);   // RNE
    return (u16)(u >> 16);
}

// ================= fused prep: invert frames + transform q/k/v =================
// grid: B * S/16 blocks. Block handles one b and 16 particles (all 8 heads).
__global__ __launch_bounds__(256) void k_prep(
    const float* __restrict__ q, const float* __restrict__ k,
    const float* __restrict__ v, const float* __restrict__ lf,
    u16* __restrict__ qg, u16* __restrict__ kg, u16* __restrict__ vtg)
{
    __shared__ float ilds[16 * 17];       // 16 inverses, stride 17 (conflict pad)
    __shared__ u16 vt[8 * 16 * 68];       // [h][nl][c], stride 68 (~17.4 KB)

    const int b  = blockIdx.x >> 5;
    const int n0 = (blockIdx.x & 31) << 4;
    const int t  = threadIdx.x;

    if (t < 16) {                         // one 4x4 adjugate inverse per thread
        const float* m = lf + ((size_t)(b * S_ + n0 + t)) * 16;
        float a[16];
#pragma unroll
        for (int j = 0; j < 16; ++j) a[j] = m[j];
        float inv[16];
        inv[0]  =  a[5]*a[10]*a[15] - a[5]*a[11]*a[14] - a[9]*a[6]*a[15] + a[9]*a[7]*a[14] + a[13]*a[6]*a[11] - a[13]*a[7]*a[10];
        inv[4]  = -a[4]*a[10]*a[15] + a[4]*a[11]*a[14] + a[8]*a[6]*a[15] - a[8]*a[7]*a[14] - a[12]*a[6]*a[11] + a[12]*a[7]*a[10];
        inv[8]  =  a[4]*a[9]*a[15] - a[4]*a[11]*a[13] - a[8]*a[5]*a[15] + a[8]*a[7]*a[13] + a[12]*a[5]*a[11] - a[12]*a[7]*a[9];
        inv[12] = -a[4]*a[9]*a[14] + a[4]*a[10]*a[13] + a[8]*a[5]*a[14] - a[8]*a[6]*a[13] - a[12]*a[5]*a[10] + a[12]*a[6]*a[9];
        inv[1]  = -a[1]*a[10]*a[15] + a[1]*a[11]*a[14] + a[9]*a[2]*a[15] - a[9]*a[3]*a[14] - a[13]*a[2]*a[11] + a[13]*a[3]*a[10];
        inv[5]  =  a[0]*a[10]*a[15] - a[0]*a[11]*a[14] - a[8]*a[2]*a[15] + a[8]*a[3]*a[14] + a[12]*a[2]*a[11] - a[12]*a[3]*a[10];
        inv[9]  = -a[0]*a[9]*a[15] + a[0]*a[11]*a[13] + a[8]*a[1]*a[15] - a[8]*a[3]*a[13] - a[12]*a[1]*a[11] + a[12]*a[3]*a[9];
        inv[13] =  a[0]*a[9]*a[14] - a[0]*a[10]*a[13] - a[8]*a[1]*a[14] + a[8]*a[2]*a[13] + a[12]*a[1]*a[10] - a[12]*a[2]*a[9];
        inv[2]  =  a[1]*a[6]*a[15] - a[1]*a[7]*a[14] - a[5]*a[2]*a[15] + a[5]*a[3]*a[14] + a[13]*a[2]*a[7] - a[13]*a[3]*a[6];
        inv[6]  = -a[0]*a[6]*a[15] + a[0]*a[7]*a[14] + a[4]*a[2]*a[15] - a[4]*a[3]*a[14] - a[12]*a[2]*a[7] + a[12]*a[3]*a[6];
        inv[10] =  a[0]*a[5]*a[15] - a[0]*a[7]*a[13] - a[4]*a[1]*a[15] + a[4]*a[3]*a[13] + a[12]*a[1]*a[7] - a[12]*a[3]*a[5];
        inv[14] = -a[0]*a[5]*a[14] + a[0]*a[6]*a[13] + a[4]*a[1]*a[14] - a[4]*a[2]*a[13] - a[12]*a[1]*a[6] + a[12]*a[2]*a[5];
        inv[3]  = -a[1]*a[6]*a[11] + a[1]*a[7]*a[10] + a[5]*a[2]*a[11] - a[5]*a[3]*a[10] - a[9]*a[2]*a[7] + a[9]*a[3]*a[6];
        inv[7]  =  a[0]*a[6]*a[11] - a[0]*a[7]*a[10] - a[4]*a[2]*a[11] + a[4]*a[3]*a[10] + a[8]*a[2]*a[7] - a[8]*a[3]*a[6];
        inv[11] = -a[0]*a[5]*a[11] + a[0]*a[7]*a[9] + a[4]*a[1]*a[11] - a[4]*a[3]*a[9] - a[8]*a[1]*a[7] + a[8]*a[3]*a[5];
        inv[15] =  a[0]*a[5]*a[10] - a[0]*a[6]*a[9] - a[4]*a[1]*a[10] + a[4]*a[2]*a[9] + a[8]*a[1]*a[6] - a[8]*a[2]*a[5];
        float det = a[0]*inv[0] + a[1]*inv[4] + a[2]*inv[8] + a[3]*inv[12];
        float rd = 1.0f / det;
#pragma unroll
        for (int j = 0; j < 16; ++j) ilds[t * 17 + j] = inv[j] * rd;
    }
    __syncthreads();

    const int slot = t & 15;

    // ---- q: y = inv * x, scale 1/sqrt(C) baked ----
#pragma unroll
    for (int it = 0; it < 8; ++it) {
        int rowl = (t >> 4) + (it << 4);               // 0..127 = h*16+nl
        int h = rowl >> 4, nl = rowl & 15;
        size_t row = ((size_t)(b * H_ + h)) * S_ + n0 + nl;
        f32x4 x = *((const f32x4*)q + row * 16 + slot);
        const float* M = &ilds[nl * 17];
        float y0, y1, y2, y3;
        if (slot < 4) { y0 = x[0]; y1 = x[1]; y2 = x[2]; y3 = x[3]; }
        else {
            y0 = M[0]*x[0] + M[1]*x[1] + M[2]*x[2]  + M[3]*x[3];
            y1 = M[4]*x[0] + M[5]*x[1] + M[6]*x[2]  + M[7]*x[3];
            y2 = M[8]*x[0] + M[9]*x[1] + M[10]*x[2] + M[11]*x[3];
            y3 = M[12]*x[0] + M[13]*x[1] + M[14]*x[2] + M[15]*x[3];
        }
        us4 o; o.x = f2bf(y0 * 0.125f); o.y = f2bf(y1 * 0.125f);
        o.z = f2bf(y2 * 0.125f); o.w = f2bf(y3 * 0.125f);
        *(us4*)(qg + row * C_ + slot * 4) = o;
    }
    // ---- k: y = eta*inv*eta * x ----
#pragma unroll
    for (int it = 0; it < 8; ++it) {
        int rowl = (t >> 4) + (it << 4);
        int h = rowl >> 4, nl = rowl & 15;
        size_t row = ((size_t)(b * H_ + h)) * S_ + n0 + nl;
        f32x4 x = *((const f32x4*)k + row * 16 + slot);
        const float* M = &ilds[nl * 17];
        float y0, y1, y2, y3;
        if (slot < 4) { y0 = x[0]; y1 = x[1]; y2 = x[2]; y3 = x[3]; }
        else {
            float x0 = x[0], x1 = -x[1], x2 = -x[2], x3 = -x[3];
            y0 =   M[0]*x0 + M[1]*x1 + M[2]*x2  + M[3]*x3;
            y1 = -(M[4]*x0 + M[5]*x1 + M[6]*x2  + M[7]*x3);
            y2 = -(M[8]*x0 + M[9]*x1 + M[10]*x2 + M[11]*x3);
            y3 = -(M[12]*x0 + M[13]*x1 + M[14]*x2 + M[15]*x3);
        }
        us4 o; o.x = f2bf(y0); o.y = f2bf(y1); o.z = f2bf(y2); o.w = f2bf(y3);
        *(us4*)(kg + row * C_ + slot * 4) = o;
    }
    // ---- v: y = inv * x, into LDS [h][nl][c] then transposed writeout ----
#pragma unroll
    for (int it = 0; it < 8; ++it) {
        int rowl = (t >> 4) + (it << 4);
        int h = rowl >> 4, nl = rowl & 15;
        size_t row = ((size_t)(b * H_ + h)) * S_ + n0 + nl;
        f32x4 x = *((const f32x4*)v + row * 16 + slot);
        const float* M = &ilds[nl * 17];
        float y0, y1, y2, y3;
        if (slot < 4) { y0 = x[0]; y1 = x[1]; y2 = x[2]; y3 = x[3]; }
        else {
            y0 = M[0]*x[0] + M[1]*x[1] + M[2]*x[2]  + M[3]*x[3];
            y1 = M[4]*x[0] + M[5]*x[1] + M[6]*x[2]  + M[7]*x[3];
            y2 = M[8]*x[0] + M[9]*x[1] + M[10]*x[2] + M[11]*x[3];
            y3 = M[12]*x[0] + M[13]*x[1] + M[14]*x[2] + M[15]*x[3];
        }
        us4 o; o.x = f2bf(y0); o.y = f2bf(y1); o.z = f2bf(y2); o.w = f2bf(y3);
        *(us4*)&vt[((h << 4) + nl) * 68 + slot * 4] = o;
    }
    __syncthreads();
    // writeout: vtg[bh][c][n0+nl] ; 8B (4 keys) per store
#pragma unroll
    for (int it = 0; it < 8; ++it) {
        int i = (it << 8) + t;            // 0..2047
        int nl4 = i & 3, c = (i >> 2) & 63, h = i >> 8;
        int base = ((h << 4) + nl4 * 4) * 68 + c;
        uint32_t u0 = vt[base], u1 = vt[base + 68], u2 = vt[base + 136], u3 = vt[base + 204];
        u32x2 d; d.x = u0 | (u1 << 16); d.y = u2 | (u3 << 16);
        *(u32x2*)(vtg + (((size_t)(b * H_ + h) * 64) + c) * S_ + n0 + nl4 * 4) = d;
    }
}

// ================= flash attention (transposed S/O) + in-register epilogue =================
__global__ __launch_bounds__(256) void k_attn(
    const u16* __restrict__ qg, const u16* __restrict__ kg,
    const u16* __restrict__ vtg, const float* __restrict__ lf,
    float* __restrict__ outp)
{
    __shared__ u16 klds[64 * 72];         // [key][c]            9216 B
    __shared__ u16 vtlds[80 * 72];        // [c][key], rows 64..79: ones/zeros  11520 B
    __shared__ u16 pscr[4][16 * 72];      // per-wave P [q][key]  9216 B

    const int bh = blockIdx.x & 255;      // all 8 q-chunks of a bh share an XCD's L2
    const int qc = blockIdx.x >> 8;
    const int b  = bh >> 3;
    const int tid = threadIdx.x;
    const int wave = tid >> 6;
    const int lane = tid & 63;
    const int l16 = lane & 15;
    const int g4  = lane >> 4;

    // ones row (c=64) for MFMA-computed softmax denominator; rows 65..79 zero
    {
        int row = 64 + (tid >> 4);
        u16 val = (row == 64) ? (u16)0x3F80 : (u16)0;
        us4 z; z.x = val; z.y = val; z.z = val; z.w = val;
        *(us4*)&vtlds[row * 72 + (tid & 15) * 4] = z;
    }

    u16* pw = pscr[wave];
    const int q0w = qc * 64 + wave * 16;
    const int qglob = q0w + l16;

    // Q as B-fragment: B[k=c][n=q], lane n=l16, c = g4*8+j (+32)
    const u16* qb = qg + ((size_t)(bh * S_ + qglob)) * C_ + g4 * 8;
    short8 bq0 = *(const short8*)qb;
    short8 bq1 = *(const short8*)(qb + 32);

    float mprev = -3.0e38f;
    f32x4 Ov[4], Ol;
#pragma unroll
    for (int nb = 0; nb < 4; ++nb) Ov[nb] = (f32x4){0.f, 0.f, 0.f, 0.f};
    Ol = (f32x4){0.f, 0.f, 0.f, 0.f};

    const u16* kbase = kg  + (size_t)bh * S_ * C_;
    const u16* vbase = vtg + (size_t)bh * C_ * S_;
    const float L2E = 1.4426950408889634f;

    for (int kc = 0; kc < 8; ++kc) {
        __syncthreads();
#pragma unroll
        for (int i = tid; i < 512; i += 256) {   // K chunk: 64 keys x 64 ch
            int r = i >> 3, c8 = i & 7;
            *(short8*)&klds[r * 72 + c8 * 8] =
                *(const short8*)(kbase + ((size_t)(kc * 64 + r)) * C_ + c8 * 8);
        }
#pragma unroll
        for (int i = tid; i < 512; i += 256) {   // V^T chunk: 64 ch x 64 keys
            int c = i >> 3, k8 = i & 7;
            *(short8*)&vtlds[c * 72 + k8 * 8] =
                *(const short8*)(vbase + (size_t)c * S_ + kc * 64 + k8 * 8);
        }
        __syncthreads();

        // S^T = K Q^T : C[key][q], key = nb*16 + g4*4 + r, q = l16
        f32x4 sT[4];
#pragma unroll
        for (int nb = 0; nb < 4; ++nb) {
            const u16* kr = &klds[(nb * 16 + l16) * 72 + g4 * 8];
            short8 a0 = *(const short8*)kr;
            short8 a1 = *(const short8*)(kr + 32);
            f32x4 acc = (f32x4){0.f, 0.f, 0.f, 0.f};
            acc = __builtin_amdgcn_mfma_f32_16x16x32_bf16(a0, bq0, acc, 0, 0, 0);
            acc = __builtin_amdgcn_mfma_f32_16x16x32_bf16(a1, bq1, acc, 0, 0, 0);
            sT[nb] = acc;
        }
        // column (per-q) max: 15 in-lane + 2 shuffles
        float mx = sT[0][0];
#pragma unroll
        for (int nb = 0; nb < 4; ++nb)
#pragma unroll
            for (int r = 0; r < 4; ++r) mx = fmaxf(mx, sT[nb][r]);
        mx = fmaxf(mx, __shfl_xor(mx, 16));
        mx = fmaxf(mx, __shfl_xor(mx, 32));
        float nm = fmaxf(mprev, mx);
        float alpha = exp2f((mprev - nm) * L2E);
        mprev = nm;

        // P^T -> P[q][key] rows in LDS; 4 consecutive keys packed per b64 write
#pragma unroll
        for (int nb = 0; nb < 4; ++nb) {
            u16 p0 = f2bf(exp2f((sT[nb][0] - nm) * L2E));
            u16 p1 = f2bf(exp2f((sT[nb][1] - nm) * L2E));
            u16 p2 = f2bf(exp2f((sT[nb][2] - nm) * L2E));
            u16 p3 = f2bf(exp2f((sT[nb][3] - nm) * L2E));
            u32x2 d; d.x = (uint32_t)p0 | ((uint32_t)p1 << 16);
            d.y = (uint32_t)p2 | ((uint32_t)p3 << 16);
            *(u32x2*)&pw[l16 * 72 + nb * 16 + g4 * 4] = d;
        }
        // rescale accumulators (alpha uniform per q-column)
#pragma unroll
        for (int nb = 0; nb < 4; ++nb)
#pragma unroll
            for (int r = 0; r < 4; ++r) Ov[nb][r] *= alpha;
#pragma unroll
        for (int r = 0; r < 4; ++r) Ol[r] *= alpha;

        // O^T += V^T P^T : A = V^T rows (c), B = P rows (q); denominator via ones-row
        short8 bp0 = *(const short8*)&pw[l16 * 72 + g4 * 8];
        short8 bp1 = *(const short8*)&pw[l16 * 72 + 32 + g4 * 8];
#pragma unroll
        for (int nb = 0; nb < 4; ++nb) {
            const u16* vr = &vtlds[(nb * 16 + l16) * 72 + g4 * 8];
            short8 a0 = *(const short8*)vr;
            short8 a1 = *(const short8*)(vr + 32);
            Ov[nb] = __builtin_amdgcn_mfma_f32_16x16x32_bf16(a0, bp0, Ov[nb], 0, 0, 0);
            Ov[nb] = __builtin_amdgcn_mfma_f32_16x16x32_bf16(a1, bp1, Ov[nb], 0, 0, 0);
        }
        {
            const u16* lr = &vtlds[(64 + l16) * 72 + g4 * 8];
            short8 a0 = *(const short8*)lr;
            short8 a1 = *(const short8*)(lr + 32);
            Ol = __builtin_amdgcn_mfma_f32_16x16x32_bf16(a0, bp0, Ol, 0, 0, 0);
            Ol = __builtin_amdgcn_mfma_f32_16x16x32_bf16(a1, bp1, Ol, 0, 0, 0);
        }
    }

    // epilogue: denominator from ones-row (m=64 lives in lane group g4=0, reg 0)
    float l = __shfl(Ol[0], l16);
    float il = 1.0f / l;
    const float* L = lf + ((size_t)(b * S_ + qglob)) * 16;
    float* ob = outp + ((size_t)(bh * S_ + qglob)) * C_;
#pragma unroll
    for (int nb = 0; nb < 4; ++nb) {
        float x0 = Ov[nb][0] * il, x1 = Ov[nb][1] * il,
              x2 = Ov[nb][2] * il, x3 = Ov[nb][3] * il;
        float y0, y1, y2, y3;
        if (nb == 0) {           // channels 0..15: scalars pass through
            y0 = x0; y1 = x1; y2 = x2; y3 = x3;
        } else {                 // channel quad (nb*16+g4*4) is one Lorentz 4-vector
            y0 = L[0]*x0 + L[1]*x1 + L[2]*x2  + L[3]*x3;
            y1 = L[4]*x0 + L[5]*x1 + L[6]*x2  + L[7]*x3;
            y2 = L[8]*x0 + L[9]*x1 + L[10]*x2 + L[11]*x3;
            y3 = L[12]*x0 + L[13]*x1 + L[14]*x2 + L[15]*x3;
        }
        *(f32x4*)(ob + nb * 16 + g4 * 4) = (f32x4){y0, y1, y2, y3};
    }
}

extern "C" void kernel_launch(void* const* d_in, const int* in_sizes, int n_in,
                              void* d_out, int out_size, void* d_ws, size_t ws_size,
                              hipStream_t stream) {
    const float* q  = (const float*)d_in[0];
    const float* k  = (const float*)d_in[1];
    const float* v  = (const float*)d_in[2];
    const float* lf = (const float*)d_in[3];
    float* out = (float*)d_out;

    char* w = (char*)d_ws;
    u16* qg  = (u16*)w;                    // 16 MiB
    u16* kg  = (u16*)(w + (16u << 20));    // 16 MiB
    u16* vtg = (u16*)(w + (32u << 20));    // 16 MiB, transposed [bh][c][n]

    k_prep<<<B_ * (S_ / 16), 256, 0, stream>>>(q, k, v, lf, qg, kg, vtg);
    k_attn<<<2048, 256, 0, stream>>>(qg, kg, vtg, lf, out);
}

// Round 4
// 196.493 us; speedup vs baseline: 1.1297x; 1.0328x over previous
//
#include <hip/hip_runtime.h>
#include <hip/hip_bf16.h>
#include <cstdint>

typedef unsigned short u16;
typedef __attribute__((ext_vector_type(8))) short short8;
typedef __attribute__((ext_vector_type(4))) float f32x4;

#define B_ 32
#define H_ 8
#define S_ 512
#define C_ 64

struct alignas(8) us4 { u16 x, y, z, w; };
struct alignas(8) u32x2 { uint32_t x, y; };

__device__ __forceinline__ u16 f2bf(float f) {
    uint32_t u = __builtin_bit_cast(uint32_t, f);
    u += 0x7fffu + ((u >> 16) & 1u);   // RNE
    return (u16)(u >> 16);
}
__device__ __forceinline__ float bf2f(u16 h) {
    uint32_t u = ((uint32_t)h) << 16;
    return __builtin_bit_cast(float, u);
}

// ================= fused prep: invert frames + transform q/k/v =================
__global__ __launch_bounds__(256) void k_prep(
    const float* __restrict__ q, const float* __restrict__ k,
    const float* __restrict__ v, const float* __restrict__ lf,
    u16* __restrict__ qg, u16* __restrict__ kg, u16* __restrict__ vtg)
{
    __shared__ float ilds[16 * 17];
    __shared__ u16 vt[8 * 16 * 68];

    const int b  = blockIdx.x >> 5;
    const int n0 = (blockIdx.x & 31) << 4;
    const int t  = threadIdx.x;

    if (t < 16) {
        const float* m = lf + ((size_t)(b * S_ + n0 + t)) * 16;
        float a[16];
#pragma unroll
        for (int j = 0; j < 16; ++j) a[j] = m[j];
        float inv[16];
        inv[0]  =  a[5]*a[10]*a[15] - a[5]*a[11]*a[14] - a[9]*a[6]*a[15] + a[9]*a[7]*a[14] + a[13]*a[6]*a[11] - a[13]*a[7]*a[10];
        inv[4]  = -a[4]*a[10]*a[15] + a[4]*a[11]*a[14] + a[8]*a[6]*a[15] - a[8]*a[7]*a[14] - a[12]*a[6]*a[11] + a[12]*a[7]*a[10];
        inv[8]  =  a[4]*a[9]*a[15] - a[4]*a[11]*a[13] - a[8]*a[5]*a[15] + a[8]*a[7]*a[13] + a[12]*a[5]*a[11] - a[12]*a[7]*a[9];
        inv[12] = -a[4]*a[9]*a[14] + a[4]*a[10]*a[13] + a[8]*a[5]*a[14] - a[8]*a[6]*a[13] - a[12]*a[5]*a[10] + a[12]*a[6]*a[9];
        inv[1]  = -a[1]*a[10]*a[15] + a[1]*a[11]*a[14] + a[9]*a[2]*a[15] - a[9]*a[3]*a[14] - a[13]*a[2]*a[11] + a[13]*a[3]*a[10];
        inv[5]  =  a[0]*a[10]*a[15] - a[0]*a[11]*a[14] - a[8]*a[2]*a[15] + a[8]*a[3]*a[14] + a[12]*a[2]*a[11] - a[12]*a[3]*a[10];
        inv[9]  = -a[0]*a[9]*a[15] + a[0]*a[11]*a[13] + a[8]*a[1]*a[15] - a[8]*a[3]*a[13] - a[12]*a[1]*a[11] + a[12]*a[3]*a[9];
        inv[13] =  a[0]*a[9]*a[14] - a[0]*a[10]*a[13] - a[8]*a[1]*a[14] + a[8]*a[2]*a[13] + a[12]*a[1]*a[10] - a[12]*a[2]*a[9];
        inv[2]  =  a[1]*a[6]*a[15] - a[1]*a[7]*a[14] - a[5]*a[2]*a[15] + a[5]*a[3]*a[14] + a[13]*a[2]*a[7] - a[13]*a[3]*a[6];
        inv[6]  = -a[0]*a[6]*a[15] + a[0]*a[7]*a[14] + a[4]*a[2]*a[15] - a[4]*a[3]*a[14] - a[12]*a[2]*a[7] + a[12]*a[3]*a[6];
        inv[10] =  a[0]*a[5]*a[15] - a[0]*a[7]*a[13] - a[4]*a[1]*a[15] + a[4]*a[3]*a[13] + a[12]*a[1]*a[7] - a[12]*a[3]*a[5];
        inv[14] = -a[0]*a[5]*a[14] + a[0]*a[6]*a[13] + a[4]*a[1]*a[14] - a[4]*a[2]*a[13] - a[12]*a[1]*a[6] + a[12]*a[2]*a[5];
        inv[3]  = -a[1]*a[6]*a[11] + a[1]*a[7]*a[10] + a[5]*a[2]*a[11] - a[5]*a[3]*a[10] - a[9]*a[2]*a[7] + a[9]*a[3]*a[6];
        inv[7]  =  a[0]*a[6]*a[11] - a[0]*a[7]*a[10] - a[4]*a[2]*a[11] + a[4]*a[3]*a[10] + a[8]*a[2]*a[7] - a[8]*a[3]*a[6];
        inv[11] = -a[0]*a[5]*a[11] + a[0]*a[7]*a[9] + a[4]*a[1]*a[11] - a[4]*a[3]*a[9] - a[8]*a[1]*a[7] + a[8]*a[3]*a[5];
        inv[15] =  a[0]*a[5]*a[10] - a[0]*a[6]*a[9] - a[4]*a[1]*a[10] + a[4]*a[2]*a[9] + a[8]*a[1]*a[6] - a[8]*a[2]*a[5];
        float det = a[0]*inv[0] + a[1]*inv[4] + a[2]*inv[8] + a[3]*inv[12];
        float rd = 1.0f / det;
#pragma unroll
        for (int j = 0; j < 16; ++j) ilds[t * 17 + j] = inv[j] * rd;
    }
    __syncthreads();

    const int slot = t & 15;

    // ---- q: y = inv * x, scale 1/sqrt(C) baked ----
#pragma unroll
    for (int it = 0; it < 8; ++it) {
        int rowl = (t >> 4) + (it << 4);
        int h = rowl >> 4, nl = rowl & 15;
        size_t row = ((size_t)(b * H_ + h)) * S_ + n0 + nl;
        f32x4 x = *((const f32x4*)q + row * 16 + slot);
        const float* M = &ilds[nl * 17];
        float y0, y1, y2, y3;
        if (slot < 4) { y0 = x[0]; y1 = x[1]; y2 = x[2]; y3 = x[3]; }
        else {
            y0 = M[0]*x[0] + M[1]*x[1] + M[2]*x[2]  + M[3]*x[3];
            y1 = M[4]*x[0] + M[5]*x[1] + M[6]*x[2]  + M[7]*x[3];
            y2 = M[8]*x[0] + M[9]*x[1] + M[10]*x[2] + M[11]*x[3];
            y3 = M[12]*x[0] + M[13]*x[1] + M[14]*x[2] + M[15]*x[3];
        }
        us4 o; o.x = f2bf(y0 * 0.125f); o.y = f2bf(y1 * 0.125f);
        o.z = f2bf(y2 * 0.125f); o.w = f2bf(y3 * 0.125f);
        *(us4*)(qg + row * C_ + slot * 4) = o;
    }
    // ---- k: y = eta*inv*eta * x ----
#pragma unroll
    for (int it = 0; it < 8; ++it) {
        int rowl = (t >> 4) + (it << 4);
        int h = rowl >> 4, nl = rowl & 15;
        size_t row = ((size_t)(b * H_ + h)) * S_ + n0 + nl;
        f32x4 x = *((const f32x4*)k + row * 16 + slot);
        const float* M = &ilds[nl * 17];
        float y0, y1, y2, y3;
        if (slot < 4) { y0 = x[0]; y1 = x[1]; y2 = x[2]; y3 = x[3]; }
        else {
            float x0 = x[0], x1 = -x[1], x2 = -x[2], x3 = -x[3];
            y0 =   M[0]*x0 + M[1]*x1 + M[2]*x2  + M[3]*x3;
            y1 = -(M[4]*x0 + M[5]*x1 + M[6]*x2  + M[7]*x3);
            y2 = -(M[8]*x0 + M[9]*x1 + M[10]*x2 + M[11]*x3);
            y3 = -(M[12]*x0 + M[13]*x1 + M[14]*x2 + M[15]*x3);
        }
        us4 o; o.x = f2bf(y0); o.y = f2bf(y1); o.z = f2bf(y2); o.w = f2bf(y3);
        *(us4*)(kg + row * C_ + slot * 4) = o;
    }
    // ---- v: y = inv * x, into LDS then transposed writeout ----
#pragma unroll
    for (int it = 0; it < 8; ++it) {
        int rowl = (t >> 4) + (it << 4);
        int h = rowl >> 4, nl = rowl & 15;
        size_t row = ((size_t)(b * H_ + h)) * S_ + n0 + nl;
        f32x4 x = *((const f32x4*)v + row * 16 + slot);
        const float* M = &ilds[nl * 17];
        float y0, y1, y2, y3;
        if (slot < 4) { y0 = x[0]; y1 = x[1]; y2 = x[2]; y3 = x[3]; }
        else {
            y0 = M[0]*x[0] + M[1]*x[1] + M[2]*x[2]  + M[3]*x[3];
            y1 = M[4]*x[0] + M[5]*x[1] + M[6]*x[2]  + M[7]*x[3];
            y2 = M[8]*x[0] + M[9]*x[1] + M[10]*x[2] + M[11]*x[3];
            y3 = M[12]*x[0] + M[13]*x[1] + M[14]*x[2] + M[15]*x[3];
        }
        us4 o; o.x = f2bf(y0); o.y = f2bf(y1); o.z = f2bf(y2); o.w = f2bf(y3);
        *(us4*)&vt[((h << 4) + nl) * 68 + slot * 4] = o;
    }
    __syncthreads();
#pragma unroll
    for (int it = 0; it < 8; ++it) {
        int i = (it << 8) + t;
        int nl4 = i & 3, c = (i >> 2) & 63, h = i >> 8;
        int base = ((h << 4) + nl4 * 4) * 68 + c;
        uint32_t u0 = vt[base], u1 = vt[base + 68], u2 = vt[base + 136], u3 = vt[base + 204];
        u32x2 d; d.x = u0 | (u1 << 16); d.y = u2 | (u3 << 16);
        *(u32x2*)(vtg + (((size_t)(b * H_ + h) * 64) + c) * S_ + n0 + nl4 * 4) = d;
    }
}

// ================= flash attention: 128 q/block, reg-prefetch pipeline =================
__global__ __launch_bounds__(256) void k_attn(
    const u16* __restrict__ qg, const u16* __restrict__ kg,
    const u16* __restrict__ vtg, const float* __restrict__ lf,
    float* __restrict__ outp)
{
    __shared__ u16 klds[64 * 72];         // [key][c]   9216 B
    __shared__ u16 vtlds[64 * 72];        // [c][key]   9216 B
    __shared__ u16 pscr[4][16 * 72];      // per-wave P [q][key]  9216 B

    const int bh = blockIdx.x & 255;      // 4 q-blocks of a bh share an XCD's L2
    const int qp = blockIdx.x >> 8;       // 0..3 : 128 queries each
    const int b  = bh >> 3;
    const int tid = threadIdx.x;
    const int wave = tid >> 6;
    const int lane = tid & 63;
    const int l16 = lane & 15;
    const int g4  = lane >> 4;

    u16* pw = pscr[wave];
    const int q0w = qp * 128 + wave * 32;       // wave covers q0w..q0w+31 (2 tiles)

    // Q as B-fragments for both tiles
    short8 bq[2][2];
#pragma unroll
    for (int t = 0; t < 2; ++t) {
        const u16* qb = qg + ((size_t)(bh * S_ + q0w + t * 16 + l16)) * C_ + g4 * 8;
        bq[t][0] = *(const short8*)qb;
        bq[t][1] = *(const short8*)(qb + 32);
    }

    float mrow[2] = {-3.0e38f, -3.0e38f};
    float lrow[2] = {0.f, 0.f};
    f32x4 Ov[2][4];
#pragma unroll
    for (int t = 0; t < 2; ++t)
#pragma unroll
        for (int nb = 0; nb < 4; ++nb) Ov[t][nb] = (f32x4){0.f, 0.f, 0.f, 0.f};

    const u16* kbase = kg  + (size_t)bh * S_ * C_;
    const u16* vbase = vtg + (size_t)bh * C_ * S_;
    const float L2E = 1.4426950408889634f;

    // staging element indices for this thread (2 each for K and V^T)
    const int i0 = tid, i1 = tid + 256;
    const int kr0r = i0 >> 3, kr0c = (i0 & 7) * 8;
    const int kr1r = i1 >> 3, kr1c = (i1 & 7) * 8;

    // prefetch chunk 0 into registers
    short8 krg[2], vrg[2];
    krg[0] = *(const short8*)(kbase + (size_t)kr0r * C_ + kr0c);
    krg[1] = *(const short8*)(kbase + (size_t)kr1r * C_ + kr1c);
    vrg[0] = *(const short8*)(vbase + (size_t)kr0r * S_ + kr0c);
    vrg[1] = *(const short8*)(vbase + (size_t)kr1r * S_ + kr1c);

    for (int kc = 0; kc < 8; ++kc) {
        __syncthreads();                        // previous chunk's consumers done
        *(short8*)&klds[kr0r * 72 + kr0c]  = krg[0];
        *(short8*)&klds[kr1r * 72 + kr1c]  = krg[1];
        *(short8*)&vtlds[kr0r * 72 + kr0c] = vrg[0];
        *(short8*)&vtlds[kr1r * 72 + kr1c] = vrg[1];
        __syncthreads();
        if (kc < 7) {                           // prefetch next chunk; drains during compute
            const u16* kb = kbase + (size_t)(kc + 1) * 64 * C_;
            const u16* vb = vbase + (kc + 1) * 64;
            krg[0] = *(const short8*)(kb + (size_t)kr0r * C_ + kr0c);
            krg[1] = *(const short8*)(kb + (size_t)kr1r * C_ + kr1c);
            vrg[0] = *(const short8*)(vb + (size_t)kr0r * S_ + kr0c);
            vrg[1] = *(const short8*)(vb + (size_t)kr1r * S_ + kr1c);
        }

#pragma unroll
        for (int t = 0; t < 2; ++t) {
            // S^T = K Q^T : C[key][q], key = nb*16 + g4*4 + r, q = l16
            f32x4 sT[4];
#pragma unroll
            for (int nb = 0; nb < 4; ++nb) {
                const u16* kr = &klds[(nb * 16 + l16) * 72 + g4 * 8];
                short8 a0 = *(const short8*)kr;
                short8 a1 = *(const short8*)(kr + 32);
                f32x4 acc = (f32x4){0.f, 0.f, 0.f, 0.f};
                acc = __builtin_amdgcn_mfma_f32_16x16x32_bf16(a0, bq[t][0], acc, 0, 0, 0);
                acc = __builtin_amdgcn_mfma_f32_16x16x32_bf16(a1, bq[t][1], acc, 0, 0, 0);
                sT[nb] = acc;
            }
            // per-q max: 15 in-lane + 2 shuffles
            float mx = sT[0][0];
#pragma unroll
            for (int nb = 0; nb < 4; ++nb)
#pragma unroll
                for (int r = 0; r < 4; ++r) mx = fmaxf(mx, sT[nb][r]);
            mx = fmaxf(mx, __shfl_xor(mx, 16));
            mx = fmaxf(mx, __shfl_xor(mx, 32));
            float nm = fmaxf(mrow[t], mx);
            float alpha = exp2f((mrow[t] - nm) * L2E);
            mrow[t] = nm;

            // P rows into wave-private LDS + in-lane denominator partials
            float rowsum = 0.f;
#pragma unroll
            for (int nb = 0; nb < 4; ++nb) {
                u16 p0 = f2bf(exp2f((sT[nb][0] - nm) * L2E));
                u16 p1 = f2bf(exp2f((sT[nb][1] - nm) * L2E));
                u16 p2 = f2bf(exp2f((sT[nb][2] - nm) * L2E));
                u16 p3 = f2bf(exp2f((sT[nb][3] - nm) * L2E));
                rowsum += bf2f(p0) + bf2f(p1) + bf2f(p2) + bf2f(p3);
                u32x2 d; d.x = (uint32_t)p0 | ((uint32_t)p1 << 16);
                d.y = (uint32_t)p2 | ((uint32_t)p3 << 16);
                *(u32x2*)&pw[l16 * 72 + nb * 16 + g4 * 4] = d;
            }
            rowsum += __shfl_xor(rowsum, 16);
            rowsum += __shfl_xor(rowsum, 32);
            lrow[t] = lrow[t] * alpha + rowsum;
#pragma unroll
            for (int nb = 0; nb < 4; ++nb)
#pragma unroll
                for (int r = 0; r < 4; ++r) Ov[t][nb][r] *= alpha;

            // O^T += V^T P^T
            short8 bp0 = *(const short8*)&pw[l16 * 72 + g4 * 8];
            short8 bp1 = *(const short8*)&pw[l16 * 72 + 32 + g4 * 8];
#pragma unroll
            for (int nb = 0; nb < 4; ++nb) {
                const u16* vr = &vtlds[(nb * 16 + l16) * 72 + g4 * 8];
                short8 a0 = *(const short8*)vr;
                short8 a1 = *(const short8*)(vr + 32);
                Ov[t][nb] = __builtin_amdgcn_mfma_f32_16x16x32_bf16(a0, bp0, Ov[t][nb], 0, 0, 0);
                Ov[t][nb] = __builtin_amdgcn_mfma_f32_16x16x32_bf16(a1, bp1, Ov[t][nb], 0, 0, 0);
            }
        }
    }

    // epilogue: normalize in-register, apply lframes, store f32
#pragma unroll
    for (int t = 0; t < 2; ++t) {
        float il = 1.0f / lrow[t];
        int qglob = q0w + t * 16 + l16;
        const float* L = lf + ((size_t)(b * S_ + qglob)) * 16;
        float* ob = outp + ((size_t)(bh * S_ + qglob)) * C_;
#pragma unroll
        for (int nb = 0; nb < 4; ++nb) {
            float x0 = Ov[t][nb][0] * il, x1 = Ov[t][nb][1] * il,
                  x2 = Ov[t][nb][2] * il, x3 = Ov[t][nb][3] * il;
            float y0, y1, y2, y3;
            if (nb == 0) {       // scalar channels pass through
                y0 = x0; y1 = x1; y2 = x2; y3 = x3;
            } else {             // channel quad nb*16+g4*4 is one Lorentz 4-vector
                y0 = L[0]*x0 + L[1]*x1 + L[2]*x2  + L[3]*x3;
                y1 = L[4]*x0 + L[5]*x1 + L[6]*x2  + L[7]*x3;
                y2 = L[8]*x0 + L[9]*x1 + L[10]*x2 + L[11]*x3;
                y3 = L[12]*x0 + L[13]*x1 + L[14]*x2 + L[15]*x3;
            }
            *(f32x4*)(ob + nb * 16 + g4 * 4) = (f32x4){y0, y1, y2, y3};
        }
    }
}

extern "C" void kernel_launch(void* const* d_in, const int* in_sizes, int n_in,
                              void* d_out, int out_size, void* d_ws, size_t ws_size,
                              hipStream_t stream) {
    const float* q  = (const float*)d_in[0];
    const float* k  = (const float*)d_in[1];
    const float* v  = (const float*)d_in[2];
    const float* lf = (const float*)d_in[3];
    float* out = (float*)d_out;

    char* w = (char*)d_ws;
    u16* qg  = (u16*)w;                    // 16 MiB
    u16* kg  = (u16*)(w + (16u << 20));    // 16 MiB
    u16* vtg = (u16*)(w + (32u << 20));    // 16 MiB, transposed [bh][c][n]

    k_prep<<<B_ * (S_ / 16), 256, 0, stream>>>(q, k, v, lf, qg, kg, vtg);
    k_attn<<<1024, 256, 0, stream>>>(qg, kg, vtg, lf, out);
}